// Round 6
// baseline (84.749 us; speedup 1.0000x reference)
//
#include <hip/hip_runtime.h>
#include <math.h>

#define NH   16
#define SQL  4096
#define SKL  4096
#define DK   64
#define QB   128
#define KB   64
#define KSPLIT 2
#define KHALF (SKL / KSPLIT)      // 2048
#define NKT   (KHALF / KB)        // 32 tiles per K-half
#define QUAD  4                   // tiles per barrier period
#define NQ    (NKT / QUAD)        // 8 quads

// Q pre-scale: MFMA then yields dot' = s * 0.5*log2(e), so exp2(dot') = exp(s/2)
#define QSCALE  0.090168440f      // 0.125 * 0.5 * log2(e)
#define UNSCALE 1.3862943611f     // 2*ln2 : dot' -> s

#define NB2      (NH * 32 * KSPLIT)   // 1024 partial blocks
#define ROWFLOAT (NB2 * QB)           // 131072 floats per row-stat array

typedef __bf16 bf16x8 __attribute__((ext_vector_type(8)));
typedef __bf16 bf16x4 __attribute__((ext_vector_type(4)));
typedef float  f32x4  __attribute__((ext_vector_type(4)));
typedef float  f32x2  __attribute__((ext_vector_type(2)));

#if __has_builtin(__builtin_amdgcn_exp2f)
#define EXP2(x) __builtin_amdgcn_exp2f(x)
#else
#define EXP2(x) exp2f(x)
#endif

static __device__ __forceinline__ f32x2 pk_fma(f32x2 a, f32x2 b, f32x2 c) {
#if __has_builtin(__builtin_elementwise_fma)
    return __builtin_elementwise_fma(a, b, c);
#else
    f32x2 r; r[0] = fmaf(a[0], b[0], c[0]); r[1] = fmaf(a[1], b[1], c[1]); return r;
#endif
}
static __device__ __forceinline__ f32x2 pk_max(f32x2 a, f32x2 b) {
#if __has_builtin(__builtin_elementwise_max)
    return __builtin_elementwise_max(a, b);
#else
    f32x2 r; r[0] = fmaxf(a[0], b[0]); r[1] = fmaxf(a[1], b[1]); return r;
#endif
}

// XOR-swizzled byte address into a [rows][64] bf16 tile (row stride 128 B).
__device__ __forceinline__ int swz(int row, int col_bytes) {
    return ((row << 7) + col_bytes) ^ ((row & 7) << 4);
}

static __device__ __forceinline__ bf16x4 cvt4(float4 v) {
    bf16x4 h;
    h[0] = (__bf16)v.x; h[1] = (__bf16)v.y; h[2] = (__bf16)v.z; h[3] = (__bf16)v.w;
    return h;
}

// Kernel 1: per-(head, q-block, k-half) streaming score statistics.
// 8 waves x 16 q-rows; K staged in 4-tile quads, double-buffered -> 1 barrier/quad.
__global__ __launch_bounds__(512, 4) void dtp_stats_mfma(const float* __restrict__ Q,
                                                         const float* __restrict__ K,
                                                         float* __restrict__ RSUM,
                                                         float* __restrict__ RMX,
                                                         float* __restrict__ RS1,
                                                         float* __restrict__ RS2) {
    __shared__ __align__(16) unsigned char Qs[QB * DK * 2];             // 16 KB
    __shared__ __align__(16) unsigned char Ks[2][QUAD][KB * DK * 2];    // 2 x 32 KB
    __shared__ float red[32];

    const int qb   = blockIdx.x;   // 0..31
    const int h    = blockIdx.y;   // 0..15
    const int half = blockIdx.z;   // 0..1
    const int tid  = threadIdx.x;
    const int lane = tid & 63;
    const int w    = tid >> 6;     // wave 0..7 -> q-rows w*16..w*16+15
    const int l15  = lane & 15;
    const int lg   = lane >> 4;    // 0..3

    const float* Qh = Q + ((size_t)h * SQL + (size_t)qb * QB) * DK;
    const float* Kh = K + ((size_t)h * SKL + (size_t)half * KHALF) * DK;

    // staging coords: float4 chunk sc4 fixed; rows sr + 32*j
    const int sc4 = tid & 15;
    const int sr  = tid >> 4;      // 0..31

    // ---- stage Q once: fp32 -> bf16 (pre-scaled), swizzled ----
    #pragma unroll
    for (int j = 0; j < 4; ++j) {
        int r = sr + 32 * j;
        const float4 v = *reinterpret_cast<const float4*>(Qh + r * DK + sc4 * 4);
        bf16x4 hv;
        hv[0] = (__bf16)(v.x * QSCALE); hv[1] = (__bf16)(v.y * QSCALE);
        hv[2] = (__bf16)(v.z * QSCALE); hv[3] = (__bf16)(v.w * QSCALE);
        *reinterpret_cast<bf16x4*>(&Qs[swz(r, sc4 * 8)]) = hv;
    }

    // ---- prologue: quad 0 -> regs -> Ks[0]; prefetch quad 1 -> regs ----
    // per quad each thread handles 8 chunks: rows sr+32j (j=0..7), tile j>>1
    float4 kq[8];
    #pragma unroll
    for (int j = 0; j < 8; ++j)
        kq[j] = *reinterpret_cast<const float4*>(Kh + (size_t)(sr + 32 * j) * DK + sc4 * 4);
    #pragma unroll
    for (int j = 0; j < 8; ++j)
        *reinterpret_cast<bf16x4*>(&Ks[0][j >> 1][swz(sr + 32 * (j & 1), sc4 * 8)]) = cvt4(kq[j]);
    #pragma unroll
    for (int j = 0; j < 8; ++j)
        kq[j] = *reinterpret_cast<const float4*>(Kh + (size_t)(QUAD * KB + sr + 32 * j) * DK + sc4 * 4);

    __syncthreads();   // Qs + Ks[0] visible

    // ---- hoisted A fragments (Q invariant across K) ----
    bf16x8 aF[2];
    {
        int r = w * 16 + l15;
        aF[0] = *reinterpret_cast<const bf16x8*>(&Qs[swz(r, 0 * 64 + lg * 16)]);
        aF[1] = *reinterpret_cast<const bf16x8*>(&Qs[swz(r, 1 * 64 + lg * 16)]);
    }

    // packed per-lane stats: pairs = acc regs (0,1)/(2,3) = rows lg*4+{0,1}/{2,3}
    f32x2 rsum01 = {0.f, 0.f}, rsum23 = {0.f, 0.f};
    f32x2 rmx01  = {-3.0e38f, -3.0e38f}, rmx23 = {-3.0e38f, -3.0e38f};
    f32x2 rs1_01 = {0.f, 0.f}, rs1_23 = {0.f, 0.f};
    f32x2 rs2_01 = {0.f, 0.f}, rs2_23 = {0.f, 0.f};

    for (int q = 0; q < NQ; ++q) {
        const int b = q & 1;

        // ---- write prefetched quad q+1 into inactive buffer; issue loads for q+2 ----
        if (q + 1 < NQ) {
            #pragma unroll
            for (int j = 0; j < 8; ++j)
                *reinterpret_cast<bf16x4*>(&Ks[b ^ 1][j >> 1][swz(sr + 32 * (j & 1), sc4 * 8)]) = cvt4(kq[j]);
            if (q + 2 < NQ) {
                const float* Kt = Kh + (size_t)(q + 2) * QUAD * KB * DK;
                #pragma unroll
                for (int j = 0; j < 8; ++j)
                    kq[j] = *reinterpret_cast<const float4*>(Kt + (size_t)(sr + 32 * j) * DK + sc4 * 4);
            }
        }

        // ---- compute 4 tiles (32 mfma, 16 fold units), no barriers inside ----
        #pragma unroll
        for (int t = 0; t < QUAD; ++t) {
            #pragma unroll
            for (int ct = 0; ct < 4; ++ct) {
                int rr = ct * 16 + l15;
                bf16x8 b0 = *reinterpret_cast<const bf16x8*>(&Ks[b][t][swz(rr, 0 * 64 + lg * 16)]);
                bf16x8 b1 = *reinterpret_cast<const bf16x8*>(&Ks[b][t][swz(rr, 1 * 64 + lg * 16)]);
                f32x4 a = {0.f, 0.f, 0.f, 0.f};
                a = __builtin_amdgcn_mfma_f32_16x16x32_bf16(aF[0], b0, a, 0, 0, 0);
                a = __builtin_amdgcn_mfma_f32_16x16x32_bf16(aF[1], b1, a, 0, 0, 0);
                f32x2 v01 = __builtin_shufflevector(a, a, 0, 1);
                f32x2 v23 = __builtin_shufflevector(a, a, 2, 3);
                rsum01 += v01; rsum23 += v23;
                rmx01 = pk_max(rmx01, v01);
                rmx23 = pk_max(rmx23, v23);
                f32x2 e01, e23;
                e01[0] = EXP2(v01[0]); e01[1] = EXP2(v01[1]);
                e23[0] = EXP2(v23[0]); e23[1] = EXP2(v23[1]);
                rs1_01 += e01; rs1_23 += e23;
                rs2_01 = pk_fma(e01, e01, rs2_01);
                rs2_23 = pk_fma(e23, e23, rs2_23);
            }
        }

        __syncthreads();   // quad q reads done; quad q+1 writes visible
    }

    // ---- reduce across the 16 column-lanes (bits 0..3 of lane id) ----
    #pragma unroll
    for (int m = 1; m < 16; m <<= 1) {
        #pragma unroll
        for (int c = 0; c < 2; ++c) {
            rsum01[c] += __shfl_xor(rsum01[c], m, 64);
            rsum23[c] += __shfl_xor(rsum23[c], m, 64);
            rmx01[c]   = fmaxf(rmx01[c], __shfl_xor(rmx01[c], m, 64));
            rmx23[c]   = fmaxf(rmx23[c], __shfl_xor(rmx23[c], m, 64));
            rs1_01[c] += __shfl_xor(rs1_01[c], m, 64);
            rs1_23[c] += __shfl_xor(rs1_23[c], m, 64);
            rs2_01[c] += __shfl_xor(rs2_01[c], m, 64);
            rs2_23[c] += __shfl_xor(rs2_23[c], m, 64);
        }
    }

    const int base = (h * 32 + qb) * KSPLIT + half;
    if (l15 == 0) {
        const size_t rb = (size_t)base * QB + (w * 16 + lg * 4);
        float4 mx = {rmx01[0] * UNSCALE, rmx01[1] * UNSCALE,
                     rmx23[0] * UNSCALE, rmx23[1] * UNSCALE};
        float4 s1 = {rs1_01[0], rs1_01[1], rs1_23[0], rs1_23[1]};
        float4 s2 = {rs2_01[0], rs2_01[1], rs2_23[0], rs2_23[1]};
        *reinterpret_cast<float4*>(&RMX[rb]) = mx;
        *reinterpret_cast<float4*>(&RS1[rb]) = s1;
        *reinterpret_cast<float4*>(&RS2[rb]) = s2;
        red[w * 4 + lg] = (rsum01[0] + rsum01[1]) + (rsum23[0] + rsum23[1]);
    }
    __syncthreads();
    if (tid == 0) {
        float bs = 0.f;
        #pragma unroll
        for (int i = 0; i < 32; ++i) bs += red[i];
        RSUM[base] = bs * UNSCALE;
    }
}

// Kernel 2: per-head, combine K-half partials per row, reduce, MLP, write t.
__global__ __launch_bounds__(256) void dtp_finalize(const float* __restrict__ RSUM,
                                                    const float* __restrict__ RMX,
                                                    const float* __restrict__ RS1,
                                                    const float* __restrict__ RS2,
                                                    const float* __restrict__ W1,
                                                    const float* __restrict__ b1,
                                                    const float* __restrict__ W2,
                                                    const float* __restrict__ b2,
                                                    float* __restrict__ out) {
    const int h   = blockIdx.x;
    const int tid = threadIdx.x;
    const float invSK  = 1.0f / (float)SKL;
    const float invSK1 = 1.0f / (float)(SKL - 1);

    float sm = 0.f, sv = 0.f;
    #pragma unroll
    for (int j = 0; j < 16; ++j) {
        int r  = tid + 256 * j;        // 0..4095
        int qb = r >> 7;
        int rr = r & 127;
        size_t b0 = ((size_t)(h * 32 + qb) * KSPLIT) * QB + rr;   // half 0
        size_t b1i = b0 + QB;                                     // half 1
        float mx = fmaxf(RMX[b0], RMX[b1i]);
        float s1 = RS1[b0] + RS1[b1i];
        float s2 = RS2[b0] + RS2[b1i];
        sm += mx;
        sv += (s2 / (s1 * s1) - invSK) * invSK1;
    }

    // rsum: 64 partials per head, summed by wave 0
    float ss = (tid < 64) ? RSUM[h * 64 + (tid & 63)] : 0.f;

    // wave-level reduction
    #pragma unroll
    for (int m = 1; m < 64; m <<= 1) {
        sm += __shfl_xor(sm, m, 64);
        sv += __shfl_xor(sv, m, 64);
        ss += __shfl_xor(ss, m, 64);
    }
    __shared__ float redm[4], redv[4], reds[4];
    const int wv = tid >> 6;
    if ((tid & 63) == 0) { redm[wv] = sm; redv[wv] = sv; reds[wv] = ss; }
    __syncthreads();

    if (tid == 0) {
        float tsm = redm[0] + redm[1] + redm[2] + redm[3];
        float tsv = redv[0] + redv[1] + redv[2] + redv[3];
        float tss = reds[0];   // only wave 0 loaded RSUM
        float mean_sim = tss / ((float)SQL * (float)SKL);
        float max_sim  = tsm / (float)SQL;
        float entropy  = tsv / (float)SQL;
        mean_sim = fminf(fmaxf(mean_sim, -10.f), 10.f);
        max_sim  = fminf(fmaxf(max_sim,  -10.f), 10.f);
        entropy  = fminf(fmaxf(entropy,    0.f), 1.f);
        float raw = b2[0];
        #pragma unroll
        for (int i = 0; i < 16; ++i) {
            float a = b1[i] + W1[i*3+0] * mean_sim + W1[i*3+1] * max_sim + W1[i*3+2] * entropy;
            raw += W2[i] * tanhf(a);
        }
        float t = 0.1f + 0.9f / (1.0f + __expf(-raw));
        t = fminf(fmaxf(t, 0.1f), 1.0f);
        out[h] = t;
    }
}

extern "C" void kernel_launch(void* const* d_in, const int* in_sizes, int n_in,
                              void* d_out, int out_size, void* d_ws, size_t ws_size,
                              hipStream_t stream) {
    const float* Q  = (const float*)d_in[0];
    const float* K  = (const float*)d_in[1];
    const float* W1 = (const float*)d_in[2];
    const float* b1 = (const float*)d_in[3];
    const float* W2 = (const float*)d_in[4];
    const float* b2 = (const float*)d_in[5];
    float* out      = (float*)d_out;

    float* RSUM = (float*)d_ws;                 // 1024 floats
    float* RMX  = RSUM + NB2;                   // 131072
    float* RS1  = RMX + ROWFLOAT;               // 131072
    float* RS2  = RS1 + ROWFLOAT;               // 131072  (total ~1.54 MB)

    dim3 grid(SQL / QB, NH, KSPLIT);  // (32, 16, 2) = 1024 blocks
    dtp_stats_mfma<<<grid, 512, 0, stream>>>(Q, K, RSUM, RMX, RS1, RS2);
    dtp_finalize<<<NH, 256, 0, stream>>>(RSUM, RMX, RS1, RS2, W1, b1, W2, b2, out);
}

// Round 7
// 76.931 us; speedup vs baseline: 1.1016x; 1.1016x over previous
//
#include <hip/hip_runtime.h>
#include <math.h>

#define NH   16
#define SQL  4096
#define SKL  4096
#define DK   64
#define QB   128
#define KB   64
#define KSPLIT 2
#define KHALF (SKL / KSPLIT)      // 2048
#define NKT   (KHALF / KB)        // 32 K-tiles per half

// Q pre-scale: MFMA then yields dot' = s * 0.5*log2(e), so exp2(dot') = exp(s/2)
#define QSCALE  0.090168440f      // 0.125 * 0.5 * log2(e)
#define UNSCALE 1.3862943611f     // 2*ln2 : dot' -> s

#define NB2      (NH * 32 * KSPLIT)   // 1024 partial blocks
#define ROWFLOAT (NB2 * QB)           // 131072 floats per row-stat array
#define STATS_BYTES ((size_t)(NB2 + 3 * ROWFLOAT) * 4)   // 1,576,960 B (16B-aligned)

#define KIMG 8192                     // K tile image: 64 rows x 128 B (swizzled)
#define QIMG 16384                    // Q tile image: 128 rows x 128 B (swizzled)
#define KPRE_BYTES ((size_t)NH * 64 * KIMG)   // 8.39 MB
#define QPRE_BYTES ((size_t)NH * 32 * QIMG)   // 8.39 MB

typedef __bf16 bf16x8 __attribute__((ext_vector_type(8)));
typedef __bf16 bf16x4 __attribute__((ext_vector_type(4)));
typedef float  f32x4  __attribute__((ext_vector_type(4)));
typedef float  f32x2  __attribute__((ext_vector_type(2)));

#if __has_builtin(__builtin_amdgcn_exp2f)
#define EXP2(x) __builtin_amdgcn_exp2f(x)
#else
#define EXP2(x) exp2f(x)
#endif

static __device__ __forceinline__ f32x2 pk_fma(f32x2 a, f32x2 b, f32x2 c) {
#if __has_builtin(__builtin_elementwise_fma)
    return __builtin_elementwise_fma(a, b, c);
#else
    f32x2 r; r[0] = fmaf(a[0], b[0], c[0]); r[1] = fmaf(a[1], b[1], c[1]); return r;
#endif
}
static __device__ __forceinline__ f32x2 pk_max(f32x2 a, f32x2 b) {
#if __has_builtin(__builtin_elementwise_max)
    return __builtin_elementwise_max(a, b);
#else
    f32x2 r; r[0] = fmaxf(a[0], b[0]); r[1] = fmaxf(a[1], b[1]); return r;
#endif
}

// XOR-swizzled byte address into a [rows][64] bf16 tile (row stride 128 B).
__device__ __forceinline__ int swz(int row, int col_bytes) {
    return ((row << 7) + col_bytes) ^ ((row & 7) << 4);
}

// async 16B global -> LDS (direct DMA, no VGPR round-trip). LDS layout linear,
// swizzle is baked into the SOURCE array (G21: both-sides-or-neither).
static __device__ __forceinline__ void gld16(void* l, const void* g) {
#if __has_builtin(__builtin_amdgcn_global_load_lds)
    __builtin_amdgcn_global_load_lds(
        (const __attribute__((address_space(1))) unsigned int*)g,
        (__attribute__((address_space(3))) unsigned int*)l,
        16, 0, 0);
#else
    *reinterpret_cast<float4*>(l) = *reinterpret_cast<const float4*>(g);
#endif
}

// Kernel 0: pre-pack Q (scaled) and K into bf16 swizzled tile images.
// One thread per 16B output chunk of each array (524288 chunks apiece).
__global__ __launch_bounds__(512) void dtp_prepack(const float* __restrict__ Q,
                                                   const float* __restrict__ K,
                                                   unsigned char* __restrict__ Qpre,
                                                   unsigned char* __restrict__ Kpre) {
    const int i   = blockIdx.x * 512 + threadIdx.x;   // 0..524287
    const int c16 = i & 7;            // 16B chunk within row (8 dims)
    const int rg  = i >> 3;           // h*4096 + row
    const int h   = rg >> 12;
    const int row = rg & 4095;

    const float* ks = K + (size_t)rg * DK + c16 * 8;
    float4 a = *reinterpret_cast<const float4*>(ks);
    float4 b = *reinterpret_cast<const float4*>(ks + 4);
    bf16x8 kv;
    kv[0]=(__bf16)a.x; kv[1]=(__bf16)a.y; kv[2]=(__bf16)a.z; kv[3]=(__bf16)a.w;
    kv[4]=(__bf16)b.x; kv[5]=(__bf16)b.y; kv[6]=(__bf16)b.z; kv[7]=(__bf16)b.w;
    *reinterpret_cast<bf16x8*>(
        &Kpre[(size_t)h * 64 * KIMG + (size_t)(row >> 6) * KIMG + swz(row & 63, c16 * 16)]) = kv;

    const float* qs = Q + (size_t)rg * DK + c16 * 8;
    float4 c = *reinterpret_cast<const float4*>(qs);
    float4 d = *reinterpret_cast<const float4*>(qs + 4);
    bf16x8 qv;
    qv[0]=(__bf16)(c.x*QSCALE); qv[1]=(__bf16)(c.y*QSCALE);
    qv[2]=(__bf16)(c.z*QSCALE); qv[3]=(__bf16)(c.w*QSCALE);
    qv[4]=(__bf16)(d.x*QSCALE); qv[5]=(__bf16)(d.y*QSCALE);
    qv[6]=(__bf16)(d.z*QSCALE); qv[7]=(__bf16)(d.w*QSCALE);
    *reinterpret_cast<bf16x8*>(
        &Qpre[(size_t)h * 32 * QIMG + (size_t)(row >> 7) * QIMG + swz(row & 127, c16 * 16)]) = qv;
}

// Kernel 1: per-(head, q-block, k-half) streaming score statistics.
// 4 waves x 32 q-rows; K tiles DMA'd via global_load_lds, double-buffered.
__global__ __launch_bounds__(256, 4) void dtp_stats_glds(const unsigned char* __restrict__ Qpre,
                                                         const unsigned char* __restrict__ Kpre,
                                                         float* __restrict__ RSUM,
                                                         float* __restrict__ RMX,
                                                         float* __restrict__ RS1,
                                                         float* __restrict__ RS2) {
    __shared__ __align__(16) unsigned char Qs[QIMG];        // 16 KB
    __shared__ __align__(16) unsigned char Ks[2][KIMG];     // 2 x 8 KB
    __shared__ float red[32];

    const int qb   = blockIdx.x;   // 0..31
    const int h    = blockIdx.y;   // 0..15
    const int half = blockIdx.z;   // 0..1
    const int tid  = threadIdx.x;
    const int lane = tid & 63;
    const int w    = tid >> 6;     // wave 0..3 -> q-rows w*32..w*32+31
    const int l15  = lane & 15;
    const int lg   = lane >> 4;    // 0..3

    const unsigned char* Qg = Qpre + (size_t)(h * 32 + qb) * QIMG;
    const unsigned char* Kg = Kpre + (size_t)h * 64 * KIMG + (size_t)half * NKT * KIMG;

    // ---- issue Q image (16KB) + K tile 0 (8KB) as direct-to-LDS DMA ----
    {
        const int off = tid * 16;
        #pragma unroll
        for (int r2 = 0; r2 < 4; ++r2)
            gld16(&Qs[off + r2 * 4096], Qg + off + r2 * 4096);
        gld16(&Ks[0][off],        Kg + off);
        gld16(&Ks[0][off + 4096], Kg + off + 4096);
    }
    __syncthreads();   // drains vmcnt -> Qs + Ks[0] valid

    // ---- hoisted A fragments (Q invariant across K) ----
    bf16x8 aF[2][2];
    #pragma unroll
    for (int rt = 0; rt < 2; ++rt) {
        int r = w * 32 + rt * 16 + l15;
        aF[rt][0] = *reinterpret_cast<const bf16x8*>(&Qs[swz(r, 0 * 64 + lg * 16)]);
        aF[rt][1] = *reinterpret_cast<const bf16x8*>(&Qs[swz(r, 1 * 64 + lg * 16)]);
    }

    // packed per-lane stats [rt][pair]: pair0 = acc regs (0,1), pair1 = (2,3)
    f32x2 rsum[2][2], rmx[2][2], rs1[2][2], rs2[2][2];
    #pragma unroll
    for (int rt = 0; rt < 2; ++rt)
        #pragma unroll
        for (int p = 0; p < 2; ++p) {
            rsum[rt][p] = (f32x2){0.f, 0.f};
            rmx[rt][p]  = (f32x2){-3.0e38f, -3.0e38f};
            rs1[rt][p]  = (f32x2){0.f, 0.f};
            rs2[rt][p]  = (f32x2){0.f, 0.f};
        }

    for (int t = 0; t < NKT; ++t) {
        const int b = t & 1;

        // ---- issue DMA for tile t+1 into inactive buffer (lands by barrier) ----
        if (t + 1 < NKT) {
            const unsigned char* Kt = Kg + (size_t)(t + 1) * KIMG;
            const int off = tid * 16;
            gld16(&Ks[b ^ 1][off],        Kt + off);
            gld16(&Ks[b ^ 1][off + 4096], Kt + off + 4096);
        }

        // ---- 32x64 score tile: 16 mfma, fold immediately ----
        #pragma unroll
        for (int ct = 0; ct < 4; ++ct) {
            int rr = ct * 16 + l15;
            bf16x8 b0 = *reinterpret_cast<const bf16x8*>(&Ks[b][swz(rr, 0 * 64 + lg * 16)]);
            bf16x8 b1 = *reinterpret_cast<const bf16x8*>(&Ks[b][swz(rr, 1 * 64 + lg * 16)]);
            #pragma unroll
            for (int rt = 0; rt < 2; ++rt) {
                f32x4 a = {0.f, 0.f, 0.f, 0.f};
                a = __builtin_amdgcn_mfma_f32_16x16x32_bf16(aF[rt][0], b0, a, 0, 0, 0);
                a = __builtin_amdgcn_mfma_f32_16x16x32_bf16(aF[rt][1], b1, a, 0, 0, 0);
                f32x2 v01 = __builtin_shufflevector(a, a, 0, 1);
                f32x2 v23 = __builtin_shufflevector(a, a, 2, 3);
                rsum[rt][0] += v01; rsum[rt][1] += v23;
                rmx[rt][0] = pk_max(rmx[rt][0], v01);
                rmx[rt][1] = pk_max(rmx[rt][1], v23);
                f32x2 e01, e23;
                e01[0] = EXP2(v01[0]); e01[1] = EXP2(v01[1]);
                e23[0] = EXP2(v23[0]); e23[1] = EXP2(v23[1]);
                rs1[rt][0] += e01; rs1[rt][1] += e23;
                rs2[rt][0] = pk_fma(e01, e01, rs2[rt][0]);
                rs2[rt][1] = pk_fma(e23, e23, rs2[rt][1]);
            }
        }

        __syncthreads();   // reads of Ks[b] done; DMA into Ks[b^1] drained
    }

    // ---- reduce across the 16 column-lanes (bits 0..3 of lane id) ----
    #pragma unroll
    for (int m = 1; m < 16; m <<= 1) {
        #pragma unroll
        for (int rt = 0; rt < 2; ++rt)
            #pragma unroll
            for (int c = 0; c < 2; ++c) {
                rsum[rt][c][0] += __shfl_xor(rsum[rt][c][0], m, 64);
                rsum[rt][c][1] += __shfl_xor(rsum[rt][c][1], m, 64);
                rmx[rt][c][0]   = fmaxf(rmx[rt][c][0], __shfl_xor(rmx[rt][c][0], m, 64));
                rmx[rt][c][1]   = fmaxf(rmx[rt][c][1], __shfl_xor(rmx[rt][c][1], m, 64));
                rs1[rt][c][0]  += __shfl_xor(rs1[rt][c][0], m, 64);
                rs1[rt][c][1]  += __shfl_xor(rs1[rt][c][1], m, 64);
                rs2[rt][c][0]  += __shfl_xor(rs2[rt][c][0], m, 64);
                rs2[rt][c][1]  += __shfl_xor(rs2[rt][c][1], m, 64);
            }
    }

    const int base = (h * 32 + qb) * KSPLIT + half;
    if (l15 == 0) {
        float bs = 0.f;
        #pragma unroll
        for (int rt = 0; rt < 2; ++rt) {
            const size_t rb = (size_t)base * QB + (w * 32 + rt * 16 + lg * 4);
            float4 mx = {rmx[rt][0][0] * UNSCALE, rmx[rt][0][1] * UNSCALE,
                         rmx[rt][1][0] * UNSCALE, rmx[rt][1][1] * UNSCALE};
            float4 s1 = {rs1[rt][0][0], rs1[rt][0][1], rs1[rt][1][0], rs1[rt][1][1]};
            float4 s2 = {rs2[rt][0][0], rs2[rt][0][1], rs2[rt][1][0], rs2[rt][1][1]};
            *reinterpret_cast<float4*>(&RMX[rb]) = mx;
            *reinterpret_cast<float4*>(&RS1[rb]) = s1;
            *reinterpret_cast<float4*>(&RS2[rb]) = s2;
            bs += (rsum[rt][0][0] + rsum[rt][0][1]) + (rsum[rt][1][0] + rsum[rt][1][1]);
        }
        red[w * 8 + lg * 2 + 0] = bs;
        red[w * 8 + lg * 2 + 1] = 0.f;
    }
    __syncthreads();
    if (tid == 0) {
        float bs = 0.f;
        #pragma unroll
        for (int i = 0; i < 32; ++i) bs += red[i];
        RSUM[base] = bs * UNSCALE;
    }
}

// Fallback (ws too small): R5's register-staged kernel, 8 waves x 16 rows.
__global__ __launch_bounds__(512, 8) void dtp_stats_reg(const float* __restrict__ Q,
                                                        const float* __restrict__ K,
                                                        float* __restrict__ RSUM,
                                                        float* __restrict__ RMX,
                                                        float* __restrict__ RS1,
                                                        float* __restrict__ RS2) {
    __shared__ __align__(16) unsigned char Qs[QB * DK * 2];
    __shared__ __align__(16) unsigned char Ks[2][KB * DK * 2];
    __shared__ float red[32];

    const int qb = blockIdx.x, h = blockIdx.y, half = blockIdx.z;
    const int tid = threadIdx.x, lane = tid & 63, w = tid >> 6;
    const int l15 = lane & 15, lg = lane >> 4;

    const float* Qh = Q + ((size_t)h * SQL + (size_t)qb * QB) * DK;
    const float* Kh = K + ((size_t)h * SKL + (size_t)half * KHALF) * DK;
    const int sc4 = tid & 15, sr = tid >> 4;

    #pragma unroll
    for (int j = 0; j < 4; ++j) {
        int r = sr + 32 * j;
        const float4 v = *reinterpret_cast<const float4*>(Qh + r * DK + sc4 * 4);
        bf16x4 hv;
        hv[0] = (__bf16)(v.x * QSCALE); hv[1] = (__bf16)(v.y * QSCALE);
        hv[2] = (__bf16)(v.z * QSCALE); hv[3] = (__bf16)(v.w * QSCALE);
        *reinterpret_cast<bf16x4*>(&Qs[swz(r, sc4 * 8)]) = hv;
    }
    float4 kreg[2];
    #pragma unroll
    for (int j = 0; j < 2; ++j)
        kreg[j] = *reinterpret_cast<const float4*>(Kh + (size_t)(sr + 32 * j) * DK + sc4 * 4);
    #pragma unroll
    for (int j = 0; j < 2; ++j) {
        int r = sr + 32 * j;
        bf16x4 hv;
        hv[0] = (__bf16)kreg[j].x; hv[1] = (__bf16)kreg[j].y;
        hv[2] = (__bf16)kreg[j].z; hv[3] = (__bf16)kreg[j].w;
        *reinterpret_cast<bf16x4*>(&Ks[0][swz(r, sc4 * 8)]) = hv;
    }
    #pragma unroll
    for (int j = 0; j < 2; ++j)
        kreg[j] = *reinterpret_cast<const float4*>(Kh + (size_t)(KB + sr + 32 * j) * DK + sc4 * 4);
    __syncthreads();

    bf16x8 aF[2];
    {
        int r = w * 16 + l15;
        aF[0] = *reinterpret_cast<const bf16x8*>(&Qs[swz(r, 0 * 64 + lg * 16)]);
        aF[1] = *reinterpret_cast<const bf16x8*>(&Qs[swz(r, 1 * 64 + lg * 16)]);
    }
    f32x2 rsum01 = {0.f,0.f}, rsum23 = {0.f,0.f};
    f32x2 rmx01 = {-3.0e38f,-3.0e38f}, rmx23 = {-3.0e38f,-3.0e38f};
    f32x2 rs1_01 = {0.f,0.f}, rs1_23 = {0.f,0.f};
    f32x2 rs2_01 = {0.f,0.f}, rs2_23 = {0.f,0.f};

    for (int kt = 0; kt < NKT; ++kt) {
        const int cur = kt & 1;
        if (kt + 1 < NKT) {
            #pragma unroll
            for (int j = 0; j < 2; ++j) {
                int r = sr + 32 * j;
                bf16x4 hv;
                hv[0] = (__bf16)kreg[j].x; hv[1] = (__bf16)kreg[j].y;
                hv[2] = (__bf16)kreg[j].z; hv[3] = (__bf16)kreg[j].w;
                *reinterpret_cast<bf16x4*>(&Ks[cur ^ 1][swz(r, sc4 * 8)]) = hv;
            }
            if (kt + 2 < NKT) {
                const float* Kt = Kh + (size_t)(kt + 2) * KB * DK;
                #pragma unroll
                for (int j = 0; j < 2; ++j)
                    kreg[j] = *reinterpret_cast<const float4*>(Kt + (size_t)(sr + 32 * j) * DK + sc4 * 4);
            }
        }
        #pragma unroll
        for (int ct = 0; ct < 4; ++ct) {
            int rr = ct * 16 + l15;
            bf16x8 b0 = *reinterpret_cast<const bf16x8*>(&Ks[cur][swz(rr, 0 * 64 + lg * 16)]);
            bf16x8 b1 = *reinterpret_cast<const bf16x8*>(&Ks[cur][swz(rr, 1 * 64 + lg * 16)]);
            f32x4 a = {0.f, 0.f, 0.f, 0.f};
            a = __builtin_amdgcn_mfma_f32_16x16x32_bf16(aF[0], b0, a, 0, 0, 0);
            a = __builtin_amdgcn_mfma_f32_16x16x32_bf16(aF[1], b1, a, 0, 0, 0);
            f32x2 v01 = __builtin_shufflevector(a, a, 0, 1);
            f32x2 v23 = __builtin_shufflevector(a, a, 2, 3);
            rsum01 += v01; rsum23 += v23;
            rmx01 = pk_max(rmx01, v01); rmx23 = pk_max(rmx23, v23);
            f32x2 e01, e23;
            e01[0] = EXP2(v01[0]); e01[1] = EXP2(v01[1]);
            e23[0] = EXP2(v23[0]); e23[1] = EXP2(v23[1]);
            rs1_01 += e01; rs1_23 += e23;
            rs2_01 = pk_fma(e01, e01, rs2_01);
            rs2_23 = pk_fma(e23, e23, rs2_23);
        }
        __syncthreads();
    }
    #pragma unroll
    for (int m = 1; m < 16; m <<= 1) {
        #pragma unroll
        for (int c = 0; c < 2; ++c) {
            rsum01[c] += __shfl_xor(rsum01[c], m, 64);
            rsum23[c] += __shfl_xor(rsum23[c], m, 64);
            rmx01[c] = fmaxf(rmx01[c], __shfl_xor(rmx01[c], m, 64));
            rmx23[c] = fmaxf(rmx23[c], __shfl_xor(rmx23[c], m, 64));
            rs1_01[c] += __shfl_xor(rs1_01[c], m, 64);
            rs1_23[c] += __shfl_xor(rs1_23[c], m, 64);
            rs2_01[c] += __shfl_xor(rs2_01[c], m, 64);
            rs2_23[c] += __shfl_xor(rs2_23[c], m, 64);
        }
    }
    const int base = (h * 32 + qb) * KSPLIT + half;
    if (l15 == 0) {
        const size_t rb = (size_t)base * QB + (w * 16 + lg * 4);
        float4 mx = {rmx01[0]*UNSCALE, rmx01[1]*UNSCALE, rmx23[0]*UNSCALE, rmx23[1]*UNSCALE};
        float4 s1 = {rs1_01[0], rs1_01[1], rs1_23[0], rs1_23[1]};
        float4 s2 = {rs2_01[0], rs2_01[1], rs2_23[0], rs2_23[1]};
        *reinterpret_cast<float4*>(&RMX[rb]) = mx;
        *reinterpret_cast<float4*>(&RS1[rb]) = s1;
        *reinterpret_cast<float4*>(&RS2[rb]) = s2;
        red[w * 4 + lg] = (rsum01[0] + rsum01[1]) + (rsum23[0] + rsum23[1]);
    }
    __syncthreads();
    if (tid == 0) {
        float bs = 0.f;
        #pragma unroll
        for (int i = 0; i < 32; ++i) bs += red[i];
        RSUM[base] = bs * UNSCALE;
    }
}

// Kernel 2: per-head, combine K-half partials per row, reduce, MLP, write t.
__global__ __launch_bounds__(256) void dtp_finalize(const float* __restrict__ RSUM,
                                                    const float* __restrict__ RMX,
                                                    const float* __restrict__ RS1,
                                                    const float* __restrict__ RS2,
                                                    const float* __restrict__ W1,
                                                    const float* __restrict__ b1,
                                                    const float* __restrict__ W2,
                                                    const float* __restrict__ b2,
                                                    float* __restrict__ out) {
    const int h   = blockIdx.x;
    const int tid = threadIdx.x;
    const float invSK  = 1.0f / (float)SKL;
    const float invSK1 = 1.0f / (float)(SKL - 1);

    float sm = 0.f, sv = 0.f;
    #pragma unroll
    for (int j = 0; j < 16; ++j) {
        int r  = tid + 256 * j;
        int qb = r >> 7;
        int rr = r & 127;
        size_t b0  = ((size_t)(h * 32 + qb) * KSPLIT) * QB + rr;
        size_t b1i = b0 + QB;
        float mx = fmaxf(RMX[b0], RMX[b1i]);
        float s1 = RS1[b0] + RS1[b1i];
        float s2 = RS2[b0] + RS2[b1i];
        sm += mx;
        sv += (s2 / (s1 * s1) - invSK) * invSK1;
    }
    float ss = (tid < 64) ? RSUM[h * 64 + (tid & 63)] : 0.f;
    #pragma unroll
    for (int m = 1; m < 64; m <<= 1) {
        sm += __shfl_xor(sm, m, 64);
        sv += __shfl_xor(sv, m, 64);
        ss += __shfl_xor(ss, m, 64);
    }
    __shared__ float redm[4], redv[4], reds[4];
    const int wv = tid >> 6;
    if ((tid & 63) == 0) { redm[wv] = sm; redv[wv] = sv; reds[wv] = ss; }
    __syncthreads();
    if (tid == 0) {
        float tsm = redm[0] + redm[1] + redm[2] + redm[3];
        float tsv = redv[0] + redv[1] + redv[2] + redv[3];
        float tss = reds[0];
        float mean_sim = tss / ((float)SQL * (float)SKL);
        float max_sim  = tsm / (float)SQL;
        float entropy  = tsv / (float)SQL;
        mean_sim = fminf(fmaxf(mean_sim, -10.f), 10.f);
        max_sim  = fminf(fmaxf(max_sim,  -10.f), 10.f);
        entropy  = fminf(fmaxf(entropy,    0.f), 1.f);
        float raw = b2[0];
        #pragma unroll
        for (int i = 0; i < 16; ++i) {
            float a = b1[i] + W1[i*3+0] * mean_sim + W1[i*3+1] * max_sim + W1[i*3+2] * entropy;
            raw += W2[i] * tanhf(a);
        }
        float t = 0.1f + 0.9f / (1.0f + __expf(-raw));
        t = fminf(fmaxf(t, 0.1f), 1.0f);
        out[h] = t;
    }
}

extern "C" void kernel_launch(void* const* d_in, const int* in_sizes, int n_in,
                              void* d_out, int out_size, void* d_ws, size_t ws_size,
                              hipStream_t stream) {
    const float* Q  = (const float*)d_in[0];
    const float* K  = (const float*)d_in[1];
    const float* W1 = (const float*)d_in[2];
    const float* b1 = (const float*)d_in[3];
    const float* W2 = (const float*)d_in[4];
    const float* b2 = (const float*)d_in[5];
    float* out      = (float*)d_out;

    float* RSUM = (float*)d_ws;
    float* RMX  = RSUM + NB2;
    float* RS1  = RMX + ROWFLOAT;
    float* RS2  = RS1 + ROWFLOAT;

    const size_t need = STATS_BYTES + QPRE_BYTES + KPRE_BYTES;
    dim3 grid(SQL / QB, NH, KSPLIT);  // (32, 16, 2) = 1024 blocks

    if (ws_size >= need) {
        unsigned char* Qpre = (unsigned char*)d_ws + STATS_BYTES;
        unsigned char* Kpre = Qpre + QPRE_BYTES;
        dtp_prepack<<<1024, 512, 0, stream>>>(Q, K, Qpre, Kpre);
        dtp_stats_glds<<<grid, 256, 0, stream>>>(Qpre, Kpre, RSUM, RMX, RS1, RS2);
    } else {
        dtp_stats_reg<<<grid, 512, 0, stream>>>(Q, K, RSUM, RMX, RS1, RS2);
    }
    dtp_finalize<<<NH, 256, 0, stream>>>(RSUM, RMX, RS1, RS2, W1, b1, W2, b2, out);
}